// Round 10
// baseline (252434.839 us; speedup 1.0000x reference)
//
#include <hip/hip_runtime.h>
#include <hip/hip_cooperative_groups.h>

#define BB 64      // batch
#define TT 256     // time
#define EE 256     // embed dim
#define NU 1024    // hidden units
#define N3 3072    // 3*NU

typedef __attribute__((ext_vector_type(8))) short bf16x8;
typedef __attribute__((ext_vector_type(4))) float f32x4;

__device__ __forceinline__ unsigned short f2bf(float f) {
    unsigned u = __float_as_uint(f);
    return (unsigned short)((u + 0x7FFFu + ((u >> 16) & 1u)) >> 16);
}

__device__ __forceinline__ unsigned long long packf2(float a, float b) {
    return (unsigned long long)__float_as_uint(a) |
           ((unsigned long long)__float_as_uint(b) << 32);
}

__device__ __forceinline__ float ld_sys_f32(const float* p) {
    return __uint_as_float(__hip_atomic_load((const unsigned*)p,
        __ATOMIC_RELAXED, __HIP_MEMORY_SCOPE_SYSTEM));
}

// L1-bypass loads (intra-XCD L2 coherence path). NOTE: consumers of the
// results must sit after an explicit s_waitcnt vmcnt(0) + sched_barrier(0).
__device__ __forceinline__ unsigned ld_sc0_u32(const unsigned* p) {
    unsigned v;
    asm volatile("global_load_dword %0, %1, off sc0\n\ts_waitcnt vmcnt(0)"
                 : "=v"(v) : "v"(p) : "memory");
    return v;
}
__device__ __forceinline__ unsigned long long ld_sc0_u64(const unsigned short* p) {
    unsigned long long v;
    asm volatile("global_load_dwordx2 %0, %1, off sc0"
                 : "=v"(v) : "v"(p) : "memory");
    return v;
}

// ---------------------------------------------------------------------------
// Kernel 0a: pack U[k][g*NU+u] -> Upack[u*3+g][k]  (fp32, unchanged)
// ---------------------------------------------------------------------------
__global__ __launch_bounds__(256) void upack_kernel(
    const float* __restrict__ U, float* __restrict__ up)
{
    __shared__ float t32[32][33];
    const int c0 = blockIdx.x * 32, k0 = blockIdx.y * 32;
    const int tx = threadIdx.x & 31, ty = threadIdx.x >> 5;
    #pragma unroll
    for (int i = 0; i < 4; ++i) {
        int k = ty + i * 8;
        t32[k][tx] = U[(size_t)(k0 + k) * N3 + c0 + tx];
    }
    __syncthreads();
    #pragma unroll
    for (int i = 0; i < 4; ++i) {
        int cl = ty + i * 8;
        int c = c0 + cl;
        int u = c & 1023, g = c >> 10;
        up[(size_t)(u * 3 + g) * NU + k0 + tx] = t32[tx][cl];
    }
}

// ---------------------------------------------------------------------------
// Kernel 0b: transpose tokens; 0c: zero control words
// ---------------------------------------------------------------------------
__global__ __launch_bounds__(64) void tokT_kernel(
    const int* __restrict__ x, int* __restrict__ xT)
{
    const int t = blockIdx.x, b = threadIdx.x;
    xT[t * BB + b] = x[b * TT + t];
}

__global__ __launch_bounds__(512) void zinit_kernel(unsigned* __restrict__ cnt)
{
    cnt[threadIdx.x] = 0u;   // claim[x*16], flags[128+x*32+s], xdone[448]
}

// ---------------------------------------------------------------------------
// Fused persistent kernel: 256 blocks x 512 threads (coop; 105KB LDS forces
// exactly 1 block/CU => pigeonhole gives exactly 32 blocks per XCD).
//
//  phase 0: claim (xcd from s_getreg(HW_REG_XCC_ID) [measured m09], slot via
//           device atomic). slot>=32 => grouping broken => 'broken' mode.
//  phase 1: xproj - all 256 blocks grid-stride the 3072 tiles (R8-proven
//           tile code), WT system stores -> LLC-fresh xpT.
//  phase 2: GLOBAL xproj barrier (256-arrival counter; fixes R9's cross-XCD
//           race where a block read tiles produced on another XCD).
//  phase 3: GRU scan, intra-XCD: slot owns units [32s,32s+32) x 3 gates,
//           K=1024, for the XCD's 8 batches. A (U bf16) in regs. h exchange
//           via the XCD's shared L2: plain uint4 stores + sc0 loads; flags
//           SYSTEM-WT (LLC-visible, so the poll's SYSTEM fallback is
//           meaningful). Double-buffered h: flag>=t+2 implies production t
//           consumed => no overwrite race.
//  All polls are bounded (fast sc0 -> SYSTEM fallback -> give-up); 'broken'
//  collapses caps so worst-case overhead is <100ms, never a hang.
// ---------------------------------------------------------------------------
__global__ __launch_bounds__(512) void gru_persist(
    const int* __restrict__ xT, const float* __restrict__ upack,
    const float* __restrict__ bias, float* xpT,
    float* __restrict__ out, const float* __restrict__ hidden,
    unsigned short* hbx, unsigned* cnt,
    const int* __restrict__ x, const float* __restrict__ emb,
    const float* __restrict__ W)
{
    __shared__ f32x4 red2[6144];            // 96 KB (scan: first 3072; xproj scratch)
    __shared__ f32x4 redS[384];             // 6 KB
    __shared__ unsigned short hstage[320] __attribute__((aligned(16)));
    __shared__ int xs[4];                   // xcd, slot, broken

    const int tid = threadIdx.x;
    const int w = tid >> 6;                 // wave 0..7 : K-eighth
    const int lane = tid & 63;

    // ---- phase 0: claim (xcd, slot) ----
    if (tid == 0) {
        unsigned xcd_r;
        asm volatile("s_getreg_b32 %0, hwreg(HW_REG_XCC_ID)" : "=s"(xcd_r));
        xcd_r &= 7u;
        unsigned slot = __hip_atomic_fetch_add(&cnt[xcd_r * 16], 1u,
                            __ATOMIC_RELAXED, __HIP_MEMORY_SCOPE_SYSTEM);
        xs[0] = (int)xcd_r;
        xs[1] = (int)(slot & 31u);
        xs[2] = (slot >= 32u) ? 1 : 0;      // grouping broken marker
    }
    __syncthreads();
    const int xcd = xs[0], slot = xs[1];

    // ---- phase 1: xproj tiles, grid-stride over all 256 blocks ----
    {
        float* AsT = (float*)red2;                 // [32][132]
        float* Ws  = (float*)red2 + 4224;          // [32][132]
        int*  toks = (int*)((float*)red2 + 8448);  // [128]
        const int tx = tid & 15, ty2 = tid >> 4;   // ty2: 0..31

        for (int idx0 = blockIdx.x; idx0 < 3072; idx0 += 256) {
            const int mt = idx0 / 24, nt = idx0 % 24;
            const int m0 = mt * 128, n0 = nt * 128;

            if (tid < 128) {
                int mg = m0 + tid;
                toks[tid] = x[(mg & 63) * TT + (mg >> 6)];
            }
            __syncthreads();

            float acc[4][8] = {};
            for (int kb = 0; kb < 8; ++kb) {
                const int k0 = kb * 32;
                if (kb) __syncthreads();
                #pragma unroll
                for (int i = 0; i < 2; ++i) {
                    int idx = tid + 512 * i;
                    int m = idx >> 3, c4 = idx & 7;
                    float4 av = *(const float4*)(emb +
                        (size_t)toks[m] * EE + k0 + c4 * 4);
                    AsT[(c4 * 4 + 0) * 132 + m] = av.x;
                    AsT[(c4 * 4 + 1) * 132 + m] = av.y;
                    AsT[(c4 * 4 + 2) * 132 + m] = av.z;
                    AsT[(c4 * 4 + 3) * 132 + m] = av.w;
                    int r = idx >> 5, w4 = idx & 31;
                    *(float4*)&Ws[r * 132 + w4 * 4] =
                        *(const float4*)(W + (size_t)(k0 + r) * N3 + n0 + w4 * 4);
                }
                __syncthreads();
                #pragma unroll 8
                for (int kk = 0; kk < 32; ++kk) {
                    float a4[4], w8[8];
                    *(float4*)a4       = *(const float4*)&AsT[kk * 132 + ty2 * 4];
                    *(float4*)w8       = *(const float4*)&Ws[kk * 132 + tx * 8];
                    *(float4*)(w8 + 4) = *(const float4*)&Ws[kk * 132 + tx * 8 + 4];
                    #pragma unroll
                    for (int i = 0; i < 4; ++i)
                        #pragma unroll
                        for (int j = 0; j < 8; ++j) acc[i][j] += a4[i] * w8[j];
                }
            }

            float b8[8];
            *(float4*)b8       = *(const float4*)(bias + n0 + tx * 8);
            *(float4*)(b8 + 4) = *(const float4*)(bias + n0 + tx * 8 + 4);
            const int t0 = mt * 2 + (ty2 >> 4);
            const int bq0 = (ty2 & 15) * 4;
            #pragma unroll
            for (int j = 0; j < 8; ++j) {
                const int c = n0 + tx * 8 + j;
                float f0 = acc[0][j] + b8[j], f1 = acc[1][j] + b8[j];
                float f2 = acc[2][j] + b8[j], f3 = acc[3][j] + b8[j];
                size_t base = ((size_t)t0 * N3 + c) * BB + bq0;
                __hip_atomic_store((unsigned long long*)(xpT + base),
                                   packf2(f0, f1),
                                   __ATOMIC_RELAXED, __HIP_MEMORY_SCOPE_SYSTEM);
                __hip_atomic_store((unsigned long long*)(xpT + base + 2),
                                   packf2(f2, f3),
                                   __ATOMIC_RELAXED, __HIP_MEMORY_SCOPE_SYSTEM);
            }
            __syncthreads();
        }
        __builtin_amdgcn_s_waitcnt(0);   // each wave: own WT stores LLC-visible
        __syncthreads();                 // whole block's xproj drained
        if (tid == 0)                    // global arrival
            __hip_atomic_fetch_add(&cnt[448], 1u,
                                   __ATOMIC_RELAXED, __HIP_MEMORY_SCOPE_SYSTEM);
    }

    // ---- GRU identities ----
    const int U0 = slot * 32;
    const int du = tid >> 3;            // 0..31 unit offset (gating threads)
    const int b  = tid & 7;             // 0..7 local batch
    const int bg = 8 * xcd + b;         // global batch

    // ---- A-fragments: 6 rowtiles (gate,half) x 4 ksteps, bf16 in regs ----
    bf16x8 af[6][4];
    #pragma unroll
    for (int rt = 0; rt < 6; ++rt) {
        const int R = (U0 + (rt & 1) * 16 + (lane & 15)) * 3 + (rt >> 1);
        #pragma unroll
        for (int s4 = 0; s4 < 4; ++s4) {
            const int k0 = w * 128 + s4 * 32 + (lane >> 4) * 8;
            const float* p = upack + (size_t)R * NU + k0;
            float4 v0 = *(const float4*)p;
            float4 v1 = *(const float4*)(p + 4);
            af[rt][s4] = (bf16x8){ (short)f2bf(v0.x), (short)f2bf(v0.y),
                                   (short)f2bf(v0.z), (short)f2bf(v0.w),
                                   (short)f2bf(v1.x), (short)f2bf(v1.y),
                                   (short)f2bf(v1.z), (short)f2bf(v1.w) };
        }
    }

    float hold = 0.f, brz = 0.f, brr = 0.f, brh = 0.f;
    if (tid < 256) {
        hold = hidden[(size_t)bg * NU + U0 + du];
        brz = bias[N3 + 0 * NU + U0 + du];
        brr = bias[N3 + 1 * NU + U0 + du];
        brh = bias[N3 + 2 * NU + U0 + du];
    }
    float* state_out = out + (size_t)BB * TT * NU;

    unsigned short* hbu = hbx + (size_t)xcd * 16384;   // this XCD's 2 buffers
    unsigned* flg = cnt + 128 + xcd * 32;              // 32 per-slot flags
    unsigned* flmy = flg + slot;

    // ---- init produce: production 0 = bf16(hidden) into buf0 ----
    if (tid < 256) hstage[b * 32 + du] = f2bf(hold);
    __syncthreads();
    if (w == 0 && lane < 32) {
        uint4 hv = *(const uint4*)&hstage[(lane & 7) * 32 + (lane >> 3) * 8];
        *(uint4*)(hbu + (size_t)slot * 256 + lane * 8) = hv;
    }
    if (w == 0) {
        asm volatile("s_waitcnt vmcnt(0)" ::: "memory");
        if (lane == 0)
            __hip_atomic_store(flmy, 1u, __ATOMIC_RELAXED,
                               __HIP_MEMORY_SCOPE_SYSTEM);
    }

    // ---- phase 2: global xproj barrier (all 256 blocks arrived) ----
    if (tid == 0) {
        long g = 0;
        for (;;) {
            unsigned v = __hip_atomic_load(&cnt[448], __ATOMIC_RELAXED,
                                           __HIP_MEMORY_SCOPE_SYSTEM);
            if (v >= 256u) break;
            if (++g > (1L << 20)) { xs[2] = 1; break; }
            __builtin_amdgcn_s_sleep(2);
        }
    }
    __syncthreads();

    // ---- init poll: all 32 slot flags >= 1 (fast sc0, SYSTEM fallback) ----
    {
        long g = 0;
        for (;;) {
            unsigned v = ld_sc0_u32(flg + (lane & 31));
            if (__all((int)(v >= 1u))) break;
            if (++g > (1L << 14)) {
                unsigned vs = __hip_atomic_load(flg + (lane & 31),
                                __ATOMIC_RELAXED, __HIP_MEMORY_SCOPE_SYSTEM);
                if (__all((int)(vs >= 1u))) break;
                if (g > (1L << 18)) { if (tid == 0) xs[2] = 1; break; }
            }
        }
    }
    __syncthreads();
    const int broken = xs[2];

    // ---- xp(0)/tok(0): SYSTEM loads (xpT LLC-fresh after barrier) ----
    float xz = 0.f, xr = 0.f, xh = 0.f; int tok = 1;
    if (tid < 256) {
        size_t xb = ((size_t)0 * N3 + U0 + du) * BB + bg;
        xz = ld_sys_f32(xpT + xb);
        xr = ld_sys_f32(xpT + xb + (size_t)NU * BB);
        xh = ld_sys_f32(xpT + xb + (size_t)2 * NU * BB);
        tok = xT[0 * BB + bg];
    }

    for (int t = 0; t < TT; ++t) {
        // ---- deferred out store for step t-1 (plain, fire-and-forget) ----
        if (tid < 256 && t > 0)
            out[((size_t)bg * TT + (t - 1)) * NU + U0 + du] = hold;

        // ---- poll: all 32 productions of step t visible (bounded) ----
        {
            const unsigned tgt = (unsigned)t + 1u;
            const long cap = broken ? (1L << 8) : (1L << 16);
            long g = 0;
            for (;;) {
                unsigned v = ld_sc0_u32(flg + (lane & 31));
                if (__all((int)(v >= tgt))) break;
                if (++g > (1L << 13)) {
                    unsigned vs = __hip_atomic_load(flg + (lane & 31),
                                    __ATOMIC_RELAXED, __HIP_MEMORY_SCOPE_SYSTEM);
                    if (__all((int)(vs >= tgt))) break;
                    if (g > cap) break;
                }
            }
        }

        // ---- B-fragments: sc0 loads from the XCD's L2 (production t) ----
        const unsigned short* hbc = hbu + (t & 1) * 8192;
        unsigned long long q[4][2];
        #pragma unroll
        for (int s4 = 0; s4 < 4; ++s4) {
            const unsigned short* p = hbc +
                (size_t)(w * 16 + s4 * 4 + (lane >> 4)) * 64 + (lane & 7) * 8;
            q[s4][0] = ld_sc0_u64(p);
            q[s4][1] = ld_sc0_u64(p + 4);
        }
        asm volatile("s_waitcnt vmcnt(0)" ::: "memory");
        __builtin_amdgcn_sched_barrier(0);
        bf16x8 bv[4];
        #pragma unroll
        for (int s4 = 0; s4 < 4; ++s4) {
            union { unsigned long long qq[2]; bf16x8 v; } uu;
            uu.qq[0] = q[s4][0]; uu.qq[1] = q[s4][1];
            bv[s4] = uu.v;
        }

        // ---- MFMA: 6 rowtiles x K=128 per wave ----
        f32x4 c6[6];
        #pragma unroll
        for (int rt = 0; rt < 6; ++rt) c6[rt] = (f32x4){0.f, 0.f, 0.f, 0.f};
        #pragma unroll
        for (int s4 = 0; s4 < 4; ++s4)
            #pragma unroll
            for (int rt = 0; rt < 6; ++rt)
                c6[rt] = __builtin_amdgcn_mfma_f32_16x16x32_bf16(
                    af[rt][s4], bv[s4], c6[rt], 0, 0, 0);

        #pragma unroll
        for (int rt = 0; rt < 6; ++rt)
            red2[w * 384 + rt * 64 + lane] = c6[rt];
        __syncthreads();

        // ---- prefetch xp/tok for t+1 (hides LLC latency behind reduce) ----
        float nxz = 0.f, nxr = 0.f, nxh = 0.f; int ntok = 1;
        if (tid < 256 && t + 1 < TT) {
            size_t xb = ((size_t)(t + 1) * N3 + U0 + du) * BB + bg;
            nxz = ld_sys_f32(xpT + xb);
            nxr = ld_sys_f32(xpT + xb + (size_t)NU * BB);
            nxh = ld_sys_f32(xpT + xb + (size_t)2 * NU * BB);
            ntok = xT[(t + 1) * BB + bg];
        }

        // ---- pass1: wave-sum (conflict-free consecutive b128) ----
        if (tid < 384) {
            f32x4 s0 = red2[tid];
            #pragma unroll
            for (int qq = 1; qq < 8; ++qq) s0 += red2[qq * 384 + tid];
            redS[tid] = s0;
        }
        __syncthreads();

        // ---- gating: unit U0+du, batch bg ----
        if (tid < 256) {
            const int r = du & 15;
            const int li = (r >> 2) * 16 + b;
            const int cc = r & 3;
            float rz = brz + ((const float*)&redS[((du >> 4) + 0) * 64 + li])[cc];
            float rr = brr + ((const float*)&redS[((du >> 4) + 2) * 64 + li])[cc];
            float rh = brh + ((const float*)&redS[((du >> 4) + 4) * 64 + li])[cc];
            float z  = 1.f / (1.f + expf(-(xz + rz)));
            float rg = 1.f / (1.f + expf(-(xr + rr)));
            float hh = tanhf(xh + rg * rh);
            float hnew = z * hold + (1.f - z) * hh;
            if (tok == 0) hnew = hold;     // mask_zero: carry state
            hstage[b * 32 + du] = f2bf(hnew);
            hold = hnew;
            xz = nxz; xr = nxr; xh = nxh; tok = ntok;
        }
        __syncthreads();

        // ---- produce h(t+1) into buf[(t+1)&1]; flag = t+2 (SYSTEM WT) ----
        if (w == 0 && t + 1 < TT) {
            if (lane < 32) {
                uint4 hv = *(const uint4*)&hstage[(lane & 7) * 32 + (lane >> 3) * 8];
                *(uint4*)(hbu + ((t + 1) & 1) * 8192 +
                          (size_t)slot * 256 + lane * 8) = hv;
            }
            asm volatile("s_waitcnt vmcnt(0)" ::: "memory");
            if (lane == 0)
                __hip_atomic_store(flmy, (unsigned)t + 2u,
                                   __ATOMIC_RELAXED, __HIP_MEMORY_SCOPE_SYSTEM);
        }
    }

    // ---- final stores: out slice TT-1 + state (plain; kernel-end flush) ----
    if (tid < 256) {
        out[((size_t)bg * TT + (TT - 1)) * NU + U0 + du] = hold;
        state_out[(size_t)bg * NU + U0 + du] = hold;
    }
}

// ---------------------------------------------------------------------------
extern "C" void kernel_launch(void* const* d_in, const int* in_sizes, int n_in,
                              void* d_out, int out_size, void* d_ws, size_t ws_size,
                              hipStream_t stream) {
    const int*   x      = (const int*)d_in[0];
    const float* hidden = (const float*)d_in[1];
    const float* emb    = (const float*)d_in[2];
    const float* W      = (const float*)d_in[3];
    const float* U      = (const float*)d_in[4];
    const float* bvec   = (const float*)d_in[5];

    float* out = (float*)d_out;

    float*          xpT   = (float*)d_ws;                     // 50,331,648 f
    float*          upck  = xpT + (size_t)16384 * N3;         //  3,145,728 f
    unsigned short* hbx   = (unsigned short*)(upck + (size_t)3 * NU * NU);
    int*            xT    = (int*)((float*)(upck + (size_t)3 * NU * NU) + 65536);
    unsigned*       cnt   = (unsigned*)(xT + TT * BB);        // 512 uints

    upack_kernel<<<dim3(96, 32), dim3(256), 0, stream>>>(U, upck);
    tokT_kernel<<<dim3(TT), dim3(64), 0, stream>>>(x, xT);
    zinit_kernel<<<dim3(1), dim3(512), 0, stream>>>(cnt);

    void* args[] = {(void*)&xT, (void*)&upck, (void*)&bvec, (void*)&xpT,
                    (void*)&out, (void*)&hidden, (void*)&hbx, (void*)&cnt,
                    (void*)&x, (void*)&emb, (void*)&W};
    hipLaunchCooperativeKernel((const void*)gru_persist, dim3(256), dim3(512),
                               args, 0, stream);
}